// Round 14
// baseline (40.121 us; speedup 1.0000x reference)
//
#include <hip/hip_runtime.h>
#include <math.h>

#define NBATCH 8192
#define NIN 64
#define NOUT 64
#define NG 17

typedef float f32x4 __attribute__((ext_vector_type(4)));

#define OUT_ELEMS   (NBATCH * NOUT)
#define EDGE_ELEMS  (NBATCH * NIN * NOUT)
#define WT_FLOATS   (NIN * NG * NOUT)
#define WT_BYTES    (WT_FLOATS * sizeof(float))

__global__ void kan_transpose_w(const float* __restrict__ W, float* __restrict__ Wt) {
    int idx = blockIdx.x * blockDim.x + threadIdx.x;
    if (idx >= NIN * NOUT * NG) return;
    int i   = idx / (NOUT * NG);
    int rem = idx - i * (NOUT * NG);
    int o   = rem / NG;
    int g   = rem - o * NG;
    Wt[(i * NG + g) * NOUT + o] = W[idx];
}

// meta: {silu, tw0, tw1, bits(g0c | g1c<<16)} — validated in R12/R13 (absmax 0.0039)
__device__ __forceinline__ f32x4 kan_meta(float xv) {
    float sig = 1.0f / (1.0f + __expf(-xv));
    float sl  = xv * sig;
    float u   = (xv + 2.5f) * 3.2f;       // spacing = 5/16 exact
    float g0f = floorf(u);
    float t   = u - g0f;
    int   g0  = (int)g0f;
    float tw0 = ((unsigned)g0       < 17u) ? (1.0f - t) : 0.0f;
    float tw1 = ((unsigned)(g0 + 1) < 17u) ? t          : 0.0f;
    int g0c = min(max(g0, 0), 16);
    int g1c = min(max(g0 + 1, 0), 16);
    f32x4 m;
    m.x = sl; m.y = tw0; m.z = tw1;
    m.w = __uint_as_float((unsigned)g0c | ((unsigned)g1c << 16));
    return m;
}

// ---------------- BASIS kernel: pure store stream, no loads in store path ----
// 512 blocks x 8 waves; each wave owns 2 consecutive rows = 8.5 KB contiguous.
#define BROWS 2
__global__ __launch_bounds__(512) void kan_basis(
    const float* __restrict__ x, float* __restrict__ basis)
{
    const int tid  = threadIdx.x;
    const int wave = tid >> 6;
    const int lane = tid & 63;
    const int row0 = (blockIdx.x * 8 + wave) * BROWS;

    __shared__ f32x4 s_meta[8][BROWS][64];   // 16 KB
    #pragma unroll
    for (int r = 0; r < BROWS; ++r)
        s_meta[wave][r][lane] = kan_meta(x[(row0 + r) * NIN + lane]);
    // same-wave LDS producer/consumer: no barrier needed

    float* bbase = basis + (size_t)row0 * (NIN * NG);
    const int NF4 = BROWS * 272;             // 544 f32x4 per wave, contiguous
    #pragma unroll
    for (int k = 0; k < (NF4 + 63) / 64; ++k) {
        int f4r = k * 64 + lane;
        if (f4r < NF4) {
            int row = (int)((unsigned)f4r / 272u);
            int rem = f4r - row * 272;
            f32x4 v;
            #pragma unroll
            for (int e = 0; e < 4; ++e) {
                int p = rem * 4 + e;
                int i = (int)((unsigned)p / 17u);
                int g = p - i * 17;
                f32x4 m = s_meta[wave][row][i];
                unsigned gg = __float_as_uint(m.w);
                v[e] = ((g == (int)(gg & 0xffffu)) ? m.y : 0.0f)
                     + ((g == (int)(gg >> 16))     ? m.z : 0.0f);
            }
            *(f32x4*)(bbase + f4r * 4) = v;
        }
    }
}

// ---------------- EDGE+OUT kernel: one long edge stream per wave -------------
// 512 blocks x 8 waves; each wave owns 2 consecutive rows = 32 KB contiguous.
#define EROWS 2
__global__ __launch_bounds__(512) void kan_edge(
    const float* __restrict__ x,
    const float* __restrict__ scale,
    const float* __restrict__ Wt,
    const float* __restrict__ bias,
    float* __restrict__ out,
    float* __restrict__ edge)
{
    const int tid  = threadIdx.x;
    const int wave = tid >> 6;
    const int lane = tid & 63;
    const int row0 = (blockIdx.x * 8 + wave) * EROWS;

    __shared__ float s_scale[NIN * NOUT];    // 16 KB
    __shared__ f32x4 s_meta[8][64];          // 8 KB

    {
        const f32x4* s4 = (const f32x4*)scale;
        f32x4* d4 = (f32x4*)s_scale;
        d4[tid]       = s4[tid];
        d4[tid + 512] = s4[tid + 512];
    }
    __syncthreads();

    const int iq = lane >> 4;
    const int o  = (lane & 15) * 4;
    f32x4 bi4 = *(const f32x4*)(bias + (lane & 15) * 4);
    f32x4 outv[EROWS];

    #pragma unroll
    for (int r = 0; r < EROWS; ++r) {
        const int b = row0 + r;
        s_meta[wave][lane] = kan_meta(x[b * NIN + lane]);
        // same-wave LDS: ordered within wave, no barrier

        f32x4 acc = {0.f, 0.f, 0.f, 0.f};
        float* erow = edge + (size_t)b * (NIN * NOUT);

        f32x4 m_n = s_meta[wave][iq];
        unsigned gg_n = __float_as_uint(m_n.w);
        f32x4 w0_n = *(const f32x4*)(Wt + (iq * NG + (int)(gg_n & 0xffffu)) * NOUT + o);
        f32x4 w1_n = *(const f32x4*)(Wt + (iq * NG + (int)(gg_n >> 16))     * NOUT + o);

        #pragma unroll
        for (int ib = 0; ib < NIN; ib += 4) {
            f32x4 m  = m_n;
            f32x4 w0 = w0_n;
            f32x4 w1 = w1_n;
            if (ib + 4 < NIN) {              // 1-deep pipeline: next iter's loads
                int i = ib + 4 + iq;
                m_n = s_meta[wave][i];
                unsigned gg = __float_as_uint(m_n.w);
                w0_n = *(const f32x4*)(Wt + (i * NG + (int)(gg & 0xffffu)) * NOUT + o);
                w1_n = *(const f32x4*)(Wt + (i * NG + (int)(gg >> 16))     * NOUT + o);
            }
            f32x4 sc = *(const f32x4*)(s_scale + (ib + iq) * NOUT + o);
            f32x4 v = m.x * sc + m.y * w0 + m.z * w1;
            *(f32x4*)(erow + ib * NOUT + lane * 4) = v;   // 1KB/wave-instr, contiguous
            acc += v;
        }
        #pragma unroll
        for (int e = 0; e < 4; ++e) {
            float a = acc[e];
            a += __shfl_xor(a, 16);
            a += __shfl_xor(a, 32);
            acc[e] = a;
        }
        outv[r] = acc * 0.125f + bi4;        // 1/sqrt(64) = 0.125 exact
    }
    if (lane < 16) {                         // out rows consecutive: 2 stores back-to-back
        #pragma unroll
        for (int r = 0; r < EROWS; ++r)
            *(f32x4*)(out + (size_t)(row0 + r) * NOUT + lane * 4) = outv[r];
    }
}

extern "C" void kernel_launch(void* const* d_in, const int* in_sizes, int n_in,
                              void* d_out, int out_size, void* d_ws, size_t ws_size,
                              hipStream_t stream) {
    const float* x     = (const float*)d_in[0];
    const float* scale = (const float*)d_in[1];
    const float* W     = (const float*)d_in[2];
    const float* bias  = (const float*)d_in[3];

    float* out   = (float*)d_out;
    float* edge  = out + OUT_ELEMS;
    float* basis = edge + EDGE_ELEMS;

    float* Wt = (float*)d_ws;
    const int n = NIN * NOUT * NG;
    if (ws_size >= WT_BYTES) {
        kan_transpose_w<<<(n + 255) / 256, 256, 0, stream>>>(W, Wt);
        kan_edge<<<dim3(NBATCH / (8 * EROWS)), dim3(512), 0, stream>>>(x, scale, Wt, bias, out, edge);
        kan_basis<<<dim3(NBATCH / (8 * BROWS)), dim3(512), 0, stream>>>(x, basis);
    }
}

// Round 15
// 38.220 us; speedup vs baseline: 1.0497x; 1.0497x over previous
//
#include <hip/hip_runtime.h>
#include <math.h>

#define NBATCH 8192
#define NIN 64
#define NOUT 64
#define NG 17

typedef float f32x4 __attribute__((ext_vector_type(4)));

// d_out layout (flat, f32): output[8192*64] | edge[8192*64*64] | basis[8192*64*17]
#define OUT_ELEMS   (NBATCH * NOUT)
#define EDGE_ELEMS  (NBATCH * NIN * NOUT)
#define WT_FLOATS   (NIN * NG * NOUT)
#define WT_BYTES    (WT_FLOATS * sizeof(float))

__global__ void kan_transpose_w(const float* __restrict__ W, float* __restrict__ Wt) {
    int idx = blockIdx.x * blockDim.x + threadIdx.x;
    if (idx >= NIN * NOUT * NG) return;
    int i   = idx / (NOUT * NG);
    int rem = idx - i * (NOUT * NG);
    int o   = rem / NG;
    int g   = rem - o * NG;
    Wt[(i * NG + g) * NOUT + o] = W[idx];
}

// 8 waves/block = 8 rows; scale in LDS; phase 3 fully decouples loads from
// stores: 16 unconditional Wt loads batch-issued (addresses from LDS offset
// table, no per-iter dependency), then 8 FMA+store bursts drain vmcnt
// incrementally. Store stream is never gated on a just-issued load.
__global__ __launch_bounds__(512) void kan_kernel(
    const float* __restrict__ x,      // [B, 64]
    const float* __restrict__ scale,  // [64, 64]
    const float* __restrict__ Wt,     // [64, 17, 64] (transposed)
    const float* __restrict__ bias,   // [64]
    float* __restrict__ out,          // [B, 64]
    float* __restrict__ edge,         // [B, 64, 64]
    float* __restrict__ basis)        // [B, 64, 17]
{
    const int tid  = threadIdx.x;
    const int wave = tid >> 6;
    const int lane = tid & 63;
    const int b = blockIdx.x * 8 + wave;

    __shared__ float s_scale[NIN * NOUT];   // 16 KB
    __shared__ f32x4 s_meta[8][64];         // {silu, tw0, tw1, -} 8 KB
    __shared__ int   s_off0[8][64];         // (i*17+g0c)*64 precomputed, 2 KB
    __shared__ int   s_off1[8][64];         // (i*17+g1c)*64, 2 KB

    // ---- stage scale into LDS ----
    {
        const f32x4* s4 = (const f32x4*)scale;
        f32x4* d4 = (f32x4*)s_scale;
        d4[tid]       = s4[tid];
        d4[tid + 512] = s4[tid + 512];
    }

    // ---- phase 1: per-input meta (lane == i), masked weights + clamped offs ----
    {
        float xv  = x[b * NIN + lane];
        float sig = 1.0f / (1.0f + __expf(-xv));
        float sl  = xv * sig;
        float u   = (xv + 2.5f) * 3.2f;       // spacing = 5/16 exact
        float g0f = floorf(u);
        float t   = u - g0f;
        int   g0  = (int)g0f;
        float tw0 = ((unsigned)g0       < 17u) ? (1.0f - t) : 0.0f;
        float tw1 = ((unsigned)(g0 + 1) < 17u) ? t          : 0.0f;
        int g0c = min(max(g0, 0), 16);
        int g1c = min(max(g0 + 1, 0), 16);
        f32x4 m;
        m.x = sl; m.y = tw0; m.z = tw1;
        m.w = __uint_as_float((unsigned)g0c | ((unsigned)g1c << 16));
        s_meta[wave][lane] = m;
        s_off0[wave][lane] = (lane * NG + g0c) * NOUT;
        s_off1[wave][lane] = (lane * NG + g1c) * NOUT;
    }
    __syncthreads();

    // ---- phase 2: basis writes (272 f32x4 per row), pure stores ----
    {
        float* brow = basis + (size_t)b * (NIN * NG);
        #pragma unroll
        for (int k = 0; k < 4; ++k) {
            int p0 = (k * 64 + lane) * 4;
            f32x4 v;
            #pragma unroll
            for (int e = 0; e < 4; ++e) {
                int p = p0 + e;
                int i = (int)((unsigned)p / 17u);
                int g = p - i * 17;
                f32x4 m = s_meta[wave][i];
                unsigned gg = __float_as_uint(m.w);
                v[e] = ((g == (int)(gg & 0xffffu)) ? m.y : 0.0f)
                     + ((g == (int)(gg >> 16))     ? m.z : 0.0f);
            }
            *(f32x4*)(brow + p0) = v;
        }
        if (lane < 16) {
            int p0 = (256 + lane) * 4;
            f32x4 v;
            #pragma unroll
            for (int e = 0; e < 4; ++e) {
                int p = p0 + e;
                int i = (int)((unsigned)p / 17u);
                int g = p - i * 17;
                f32x4 m = s_meta[wave][i];
                unsigned gg = __float_as_uint(m.w);
                v[e] = ((g == (int)(gg & 0xffffu)) ? m.y : 0.0f)
                     + ((g == (int)(gg >> 16))     ? m.z : 0.0f);
            }
            *(f32x4*)(brow + p0) = v;
        }
    }

    // ---- phase 3: edge stores, batch-issued loads then store bursts ----
    f32x4 acc = {0.f, 0.f, 0.f, 0.f};
    float* erow = edge + (size_t)b * (NIN * NOUT);
    const int iq = lane >> 4;
    const int o  = (lane & 15) * 4;

    #pragma unroll
    for (int h = 0; h < 2; ++h) {
        const int ibase = h * 32;
        f32x4 w0v[8], w1v[8];
        // batch-issue 16 independent loads (addresses from LDS table only)
        #pragma unroll
        for (int k = 0; k < 8; ++k) {
            int i = ibase + k * 4 + iq;
            w0v[k] = *(const f32x4*)(Wt + s_off0[wave][i] + o);
            w1v[k] = *(const f32x4*)(Wt + s_off1[wave][i] + o);
        }
        // FMA + store burst; vmcnt drains incrementally per k
        #pragma unroll
        for (int k = 0; k < 8; ++k) {
            int i = ibase + k * 4 + iq;
            f32x4 m  = s_meta[wave][i];
            f32x4 sc = *(const f32x4*)(s_scale + i * NOUT + o);
            f32x4 v = m.x * sc + m.y * w0v[k] + m.z * w1v[k];
            *(f32x4*)(erow + (ibase + k * 4) * NOUT + lane * 4) = v;
            acc += v;
        }
    }
    #pragma unroll
    for (int e = 0; e < 4; ++e) {
        float a = acc[e];
        a += __shfl_xor(a, 16);
        a += __shfl_xor(a, 32);
        acc[e] = a;
    }
    if (lane < 16) {
        f32x4 bi = *(const f32x4*)(bias + lane * 4);
        f32x4 r = acc * 0.125f + bi;      // 1/sqrt(64) = 0.125 exact
        *(f32x4*)(out + (size_t)b * NOUT + lane * 4) = r;
    }
}

extern "C" void kernel_launch(void* const* d_in, const int* in_sizes, int n_in,
                              void* d_out, int out_size, void* d_ws, size_t ws_size,
                              hipStream_t stream) {
    const float* x     = (const float*)d_in[0];
    const float* scale = (const float*)d_in[1];
    const float* W     = (const float*)d_in[2];
    const float* bias  = (const float*)d_in[3];

    float* out   = (float*)d_out;
    float* edge  = out + OUT_ELEMS;
    float* basis = edge + EDGE_ELEMS;

    float* Wt = (float*)d_ws;
    const int n = NIN * NOUT * NG;
    if (ws_size >= WT_BYTES) {
        kan_transpose_w<<<(n + 255) / 256, 256, 0, stream>>>(W, Wt);
        kan_kernel<<<dim3(NBATCH / 8), dim3(512), 0, stream>>>(x, scale, Wt, bias, out, edge, basis);
    }
}

// Round 17
// 38.203 us; speedup vs baseline: 1.0502x; 1.0005x over previous
//
#include <hip/hip_runtime.h>
#include <math.h>

#define NBATCH 8192
#define NIN 64
#define NOUT 64
#define NG 17

typedef float f32x4 __attribute__((ext_vector_type(4)));

// d_out layout (flat, f32): output[8192*64] | edge[8192*64*64] | basis[8192*64*17]
#define OUT_ELEMS   (NBATCH * NOUT)
#define EDGE_ELEMS  (NBATCH * NIN * NOUT)
#define WT_FLOATS   (NIN * NG * NOUT)
#define WT_BYTES    (WT_FLOATS * sizeof(float))

__global__ void kan_transpose_w(const float* __restrict__ W, float* __restrict__ Wt) {
    int idx = blockIdx.x * blockDim.x + threadIdx.x;
    if (idx >= NIN * NOUT * NG) return;
    int i   = idx / (NOUT * NG);
    int rem = idx - i * (NOUT * NG);
    int o   = rem / NG;
    int g   = rem - o * NG;
    Wt[(i * NG + g) * NOUT + o] = W[idx];
}

// R13 configuration — measured best (37.9 us). 8 waves/block = 8 rows; scale
// in LDS; unconditional clamped Wt loads with 1-deep software pipeline.
__global__ __launch_bounds__(512) void kan_kernel(
    const float* __restrict__ x,      // [B, 64]
    const float* __restrict__ scale,  // [64, 64]
    const float* __restrict__ Wt,     // [64, 17, 64] (transposed)
    const float* __restrict__ bias,   // [64]
    float* __restrict__ out,          // [B, 64]
    float* __restrict__ edge,         // [B, 64, 64]
    float* __restrict__ basis)        // [B, 64, 17]
{
    const int tid  = threadIdx.x;
    const int wave = tid >> 6;
    const int lane = tid & 63;
    const int b = blockIdx.x * 8 + wave;

    __shared__ float s_scale[NIN * NOUT];   // 16 KB
    __shared__ f32x4 s_meta[8][64];         // {silu, tw0, tw1, bits(g0c|g1c<<16)} 8 KB

    // ---- stage scale into LDS ----
    {
        const f32x4* s4 = (const f32x4*)scale;
        f32x4* d4 = (f32x4*)s_scale;
        d4[tid]       = s4[tid];
        d4[tid + 512] = s4[tid + 512];
    }

    // ---- phase 1: per-input meta (lane == i), masked weights + clamped idx ----
    {
        float xv  = x[b * NIN + lane];
        float sig = 1.0f / (1.0f + __expf(-xv));
        float sl  = xv * sig;
        float u   = (xv + 2.5f) * 3.2f;       // spacing = 5/16 exact
        float g0f = floorf(u);
        float t   = u - g0f;
        int   g0  = (int)g0f;
        float tw0 = ((unsigned)g0       < 17u) ? (1.0f - t) : 0.0f;
        float tw1 = ((unsigned)(g0 + 1) < 17u) ? t          : 0.0f;
        int g0c = min(max(g0, 0), 16);
        int g1c = min(max(g0 + 1, 0), 16);
        f32x4 m;
        m.x = sl; m.y = tw0; m.z = tw1;
        m.w = __uint_as_float((unsigned)g0c | ((unsigned)g1c << 16));
        s_meta[wave][lane] = m;
    }
    __syncthreads();

    // ---- phase 2: basis writes (272 f32x4 per row), pure stores ----
    {
        float* brow = basis + (size_t)b * (NIN * NG);
        #pragma unroll
        for (int k = 0; k < 4; ++k) {
            int p0 = (k * 64 + lane) * 4;
            f32x4 v;
            #pragma unroll
            for (int e = 0; e < 4; ++e) {
                int p = p0 + e;
                int i = (int)((unsigned)p / 17u);
                int g = p - i * 17;
                f32x4 m = s_meta[wave][i];
                unsigned gg = __float_as_uint(m.w);
                int g0c = (int)(gg & 0xffffu);
                int g1c = (int)(gg >> 16);
                v[e] = ((g == g0c) ? m.y : 0.0f) + ((g == g1c) ? m.z : 0.0f);
            }
            *(f32x4*)(brow + p0) = v;
        }
        if (lane < 16) {
            int p0 = (256 + lane) * 4;
            f32x4 v;
            #pragma unroll
            for (int e = 0; e < 4; ++e) {
                int p = p0 + e;
                int i = (int)((unsigned)p / 17u);
                int g = p - i * 17;
                f32x4 m = s_meta[wave][i];
                unsigned gg = __float_as_uint(m.w);
                int g0c = (int)(gg & 0xffffu);
                int g1c = (int)(gg >> 16);
                v[e] = ((g == g0c) ? m.y : 0.0f) + ((g == g1c) ? m.z : 0.0f);
            }
            *(f32x4*)(brow + p0) = v;
        }
    }

    // ---- phase 3: edge stores, 1-deep pipelined unconditional Wt loads ----
    f32x4 acc = {0.f, 0.f, 0.f, 0.f};
    float* erow = edge + (size_t)b * (NIN * NOUT);
    const int iq = lane >> 4;
    const int o  = (lane & 15) * 4;

    f32x4 m_n = s_meta[wave][iq];
    unsigned gg_n = __float_as_uint(m_n.w);
    f32x4 w0_n = *(const f32x4*)(Wt + (iq * NG + (int)(gg_n & 0xffffu)) * NOUT + o);
    f32x4 w1_n = *(const f32x4*)(Wt + (iq * NG + (int)(gg_n >> 16))     * NOUT + o);

    #pragma unroll
    for (int ib = 0; ib < NIN; ib += 4) {
        f32x4 m  = m_n;
        f32x4 w0 = w0_n;
        f32x4 w1 = w1_n;
        if (ib + 4 < NIN) {               // issue NEXT iter's loads first
            int i = ib + 4 + iq;
            m_n = s_meta[wave][i];
            unsigned gg = __float_as_uint(m_n.w);
            w0_n = *(const f32x4*)(Wt + (i * NG + (int)(gg & 0xffffu)) * NOUT + o);
            w1_n = *(const f32x4*)(Wt + (i * NG + (int)(gg >> 16))     * NOUT + o);
        }
        f32x4 sc = *(const f32x4*)(s_scale + (ib + iq) * NOUT + o);
        f32x4 v = m.x * sc + m.y * w0 + m.z * w1;
        *(f32x4*)(erow + ib * NOUT + lane * 4) = v;   // 1KB contiguous per wave
        acc += v;
    }
    #pragma unroll
    for (int e = 0; e < 4; ++e) {
        float a = acc[e];
        a += __shfl_xor(a, 16);
        a += __shfl_xor(a, 32);
        acc[e] = a;
    }
    if (lane < 16) {
        f32x4 bi = *(const f32x4*)(bias + lane * 4);
        f32x4 r = acc * 0.125f + bi;      // 1/sqrt(64) = 0.125 exact
        *(f32x4*)(out + (size_t)b * NOUT + lane * 4) = r;
    }
}

extern "C" void kernel_launch(void* const* d_in, const int* in_sizes, int n_in,
                              void* d_out, int out_size, void* d_ws, size_t ws_size,
                              hipStream_t stream) {
    const float* x     = (const float*)d_in[0];
    const float* scale = (const float*)d_in[1];
    const float* W     = (const float*)d_in[2];
    const float* bias  = (const float*)d_in[3];

    float* out   = (float*)d_out;
    float* edge  = out + OUT_ELEMS;
    float* basis = edge + EDGE_ELEMS;

    float* Wt = (float*)d_ws;
    const int n = NIN * NOUT * NG;
    if (ws_size >= WT_BYTES) {
        kan_transpose_w<<<(n + 255) / 256, 256, 0, stream>>>(W, Wt);
        kan_kernel<<<dim3(NBATCH / 8), dim3(512), 0, stream>>>(x, scale, Wt, bias, out, edge, basis);
    }
}